// Round 5
// baseline (4010.404 us; speedup 1.0000x reference)
//
#include <hip/hip_runtime.h>

#define L_SEQ 513
#define DM 768
#define DI 1536
#define DSTATE 16
#define DTRANK 48
#define NCLS 527
#define DEPTH 24
#define NC 32     // time chunks for parallel scan
#define CLEN 17   // ceil(513/32)
#define SKI 3     // split-K for in_proj (768 = 3*256)
#define SKX 8     // split-K for x_proj  (1536 = 8*192)
#define SKO 8     // split-K for out_proj(1536 = 8*192)

typedef unsigned short u16;
typedef __bf16 bf16x8 __attribute__((ext_vector_type(8)));
typedef float f32x4 __attribute__((ext_vector_type(4)));

#define MFMA_BF16(A, B, C) __builtin_amdgcn_mfma_f32_16x16x32_bf16(A, B, C, 0, 0, 0)

__device__ inline u16 f2bf(float x) {
  unsigned u = __float_as_uint(x);
  return (u16)((u + 0x7FFFu + ((u >> 16) & 1u)) >> 16);
}
__device__ inline float bf2f(u16 h) { return __uint_as_float((unsigned)h << 16); }
__device__ inline void split2(float v, u16& h, u16& l) {
  h = f2bf(v);
  l = f2bf(v - bf2f(h));
}
// LDS offset with XOR swizzle: row of 32 u16 (4 groups of 8); spread groups by row
__device__ __forceinline__ int lofs(int row, int g) {
  int swz = (row & 3) ^ ((row >> 2) & 3);
  return row * 32 + ((g ^ swz) << 3);
}

// ---------------- weight fp32 -> bf16 hi/lo splitter ----------------
__global__ void wconvert_kernel(const float* __restrict__ src,
                                u16* __restrict__ hi, u16* __restrict__ lo,
                                long n4) {
  long i = (long)blockIdx.x * 256 + threadIdx.x;
  long stride = (long)gridDim.x * 256;
  for (; i < n4; i += stride) {
    float4 v = ((const float4*)src)[i];
    ushort4 h, l;
    split2(v.x, h.x, l.x);
    split2(v.y, h.y, l.y);
    split2(v.z, h.z, l.z);
    split2(v.w, h.w, l.w);
    ((ushort4*)hi)[i] = h;
    ((ushort4*)lo)[i] = l;
  }
}

// ---------------- patch embed + cls insert + pos add ----------------
__global__ void patch_embed_kernel(const float* __restrict__ x,
                                   const float* __restrict__ pw,
                                   const float* __restrict__ pb,
                                   const float* __restrict__ cls,
                                   const float* __restrict__ pos,
                                   float* __restrict__ hidden,
                                   float* __restrict__ residual) {
  int c = blockIdx.x * 256 + threadIdx.x;
  int s = blockIdx.y;
  if (c >= DM) return;
  float val;
  if (s == 256) {
    val = cls[c];
  } else {
    int p = s - (s > 256 ? 1 : 0);
    int gy = p >> 6, gx = p & 63;
    const float* xp = x + gy * 16 * 1024 + gx * 16;
    const float* wp = pw + c * 256;
    float acc = pb[c];
#pragma unroll 4
    for (int ky = 0; ky < 16; ++ky)
#pragma unroll
      for (int kx = 0; kx < 16; ++kx)
        acc += xp[ky * 1024 + kx] * wp[ky * 16 + kx];
    val = acc;
  }
  long idx = (long)s * DM + c;
  hidden[idx] = val + pos[idx];
  residual[idx] = 0.f;
}

// ---- residual += sum(hidden partials); hn = rmsnorm(residual)*w -> bf16 hi/lo ----
__global__ void rmsnorm_kernel(const float* __restrict__ hp, int nparts, long pstr,
                               float* __restrict__ residual,
                               u16* __restrict__ hnh, u16* __restrict__ hnl,
                               const float* __restrict__ w) {
  int t = blockIdx.x;
  float* rrow = residual + (long)t * DM;
  int tid = threadIdx.x;  // 256, DM = 3*256
  float vals[3];
  float ss = 0.f;
#pragma unroll
  for (int i = 0; i < 3; ++i) {
    int c = tid + i * 256;
    float v = rrow[c];
    for (int p = 0; p < nparts; ++p) v += hp[(long)p * pstr + (long)t * DM + c];
    vals[i] = v;
    rrow[c] = v;
    ss += v * v;
  }
#pragma unroll
  for (int o = 32; o; o >>= 1) ss += __shfl_down(ss, o, 64);
  __shared__ float sacc[4];
  if ((tid & 63) == 0) sacc[tid >> 6] = ss;
  __syncthreads();
  float tot = sacc[0] + sacc[1] + sacc[2] + sacc[3];
  float rs = rsqrtf(tot / (float)DM + 1e-5f);
#pragma unroll
  for (int i = 0; i < 3; ++i) {
    int c = tid + i * 256;
    float y = vals[i] * rs * w[c];
    u16 h, l;
    split2(y, h, l);
    hnh[(long)t * DM + c] = h;
    hnl[(long)t * DM + c] = l;
  }
}

// ---------------- 128x128 bf16 hi/lo MFMA GEMM, optional grid split-K ----------------
// C[m][n] = sum_k A[m][k]*B[n][k]; C = Ah*Bh + Ah*Bl + Al*Bh (fp32-accurate).
// z = batch*NSK + sk; partial written to C + batch*sC + sk*sP.
#define LOADSTEP(KB)                                                    \
  {                                                                     \
    int k_ = (KB) + g0 * 8;                                             \
    bool kk_ = (k_ + 8 <= kend);                                        \
    uint4 zz = {0, 0, 0, 0};                                            \
    a0h = (kk_ && am0) ? *(const uint4*)(Ahb + aoff0 + k_) : zz;        \
    a1h = (kk_ && am1) ? *(const uint4*)(Ahb + aoff1 + k_) : zz;        \
    a0l = (kk_ && am0) ? *(const uint4*)(Alb + aoff0 + k_) : zz;        \
    a1l = (kk_ && am1) ? *(const uint4*)(Alb + aoff1 + k_) : zz;        \
    b0h = (kk_ && bm0) ? *(const uint4*)(Bhb + boff0 + k_) : zz;        \
    b1h = (kk_ && bm1) ? *(const uint4*)(Bhb + boff1 + k_) : zz;        \
    b0l = (kk_ && bm0) ? *(const uint4*)(Blb + boff0 + k_) : zz;        \
    b1l = (kk_ && bm1) ? *(const uint4*)(Blb + boff1 + k_) : zz;        \
  }
#define WRITEBUF(B)                        \
  {                                        \
    *(uint4*)&SA[B][0][l0] = a0h;          \
    *(uint4*)&SA[B][0][l1] = a1h;          \
    *(uint4*)&SA[B][1][l0] = a0l;          \
    *(uint4*)&SA[B][1][l1] = a1l;          \
    *(uint4*)&SB[B][0][l0] = b0h;          \
    *(uint4*)&SB[B][0][l1] = b1h;          \
    *(uint4*)&SB[B][1][l0] = b0l;          \
    *(uint4*)&SB[B][1][l1] = b1l;          \
  }

__global__ __launch_bounds__(256) void gemm128(
    const u16* __restrict__ Ah, const u16* __restrict__ Al,
    const u16* __restrict__ Bh, const u16* __restrict__ Bl,
    float* __restrict__ C,
    int M, int N, int K, int lda, int ldb, int ldc,
    long sA, long sB, long sC,
    int NSK, int Kb, long sP,
    const float* __restrict__ bias, long sBias, int act) {
  int z = blockIdx.z;
  int batch = z / NSK, sk = z - batch * NSK;
  const u16* Ahb = Ah + (long)batch * sA;
  const u16* Alb = Al + (long)batch * sA;
  const u16* Bhb = Bh + (long)batch * sB;
  const u16* Blb = Bl + (long)batch * sB;
  float* Cb = C + (long)batch * sC + (long)sk * sP;
  const float* biasb = bias ? bias + (long)batch * sBias : nullptr;
  int ks0 = sk * Kb;
  int kend = min(ks0 + Kb, K);

  __shared__ u16 SA[2][2][128 * 32];  // [buf][hi/lo][row*32+k]
  __shared__ u16 SB[2][2][128 * 32];  // 64 KB total

  int tid = threadIdx.x;
  int m0 = blockIdx.y * 128, n0 = blockIdx.x * 128;

  // staging: 512 slots (128 rows x 4 k-groups) per matrix-half; 2 per thread
  int r0 = tid >> 2, g0 = tid & 3;
  int r1 = r0 + 64;
  int l0 = lofs(r0, g0), l1 = lofs(r1, g0);
  long aoff0 = (long)(m0 + r0) * lda, aoff1 = (long)(m0 + r1) * lda;
  long boff0 = (long)(n0 + r0) * ldb, boff1 = (long)(n0 + r1) * ldb;
  bool am0 = (m0 + r0) < M, am1 = (m0 + r1) < M;
  bool bm0 = (n0 + r0) < N, bm1 = (n0 + r1) < N;

  // fragments: 4 waves, each a 64x64 quadrant
  int lane = tid & 63, w = tid >> 6;
  int wr = w >> 1, wc = w & 1;
  int fr = lane & 15, kh = lane >> 4;
  int offA[4], offB[4];
#pragma unroll
  for (int i = 0; i < 4; ++i) {
    offA[i] = lofs(wr * 64 + i * 16 + fr, kh);
    offB[i] = lofs(wc * 64 + i * 16 + fr, kh);
  }

  f32x4 acc[4][4] = {};
  int nst = (kend - ks0 + 31) >> 5;
  uint4 a0h, a1h, a0l, a1l, b0h, b1h, b0l, b1l;
  LOADSTEP(ks0);
  WRITEBUF(0);
  if (nst > 1) LOADSTEP(ks0 + 32);
  __syncthreads();

  for (int s = 0; s < nst; ++s) {
    int b = s & 1;
    bf16x8 fah[4], fal[4], fbh[4], fbl[4];
#pragma unroll
    for (int i = 0; i < 4; ++i) {
      fah[i] = __builtin_bit_cast(bf16x8, *(const uint4*)&SA[b][0][offA[i]]);
      fal[i] = __builtin_bit_cast(bf16x8, *(const uint4*)&SA[b][1][offA[i]]);
      fbh[i] = __builtin_bit_cast(bf16x8, *(const uint4*)&SB[b][0][offB[i]]);
      fbl[i] = __builtin_bit_cast(bf16x8, *(const uint4*)&SB[b][1][offB[i]]);
    }
#pragma unroll
    for (int mi = 0; mi < 4; ++mi)
#pragma unroll
      for (int ni = 0; ni < 4; ++ni) {
        acc[mi][ni] = MFMA_BF16(fah[mi], fbh[ni], acc[mi][ni]);
        acc[mi][ni] = MFMA_BF16(fah[mi], fbl[ni], acc[mi][ni]);
        acc[mi][ni] = MFMA_BF16(fal[mi], fbh[ni], acc[mi][ni]);
      }
    if (s + 1 < nst) {
      WRITEBUF(b ^ 1);
      if (s + 2 < nst) LOADSTEP(ks0 + (s + 2) * 32);
    }
    __syncthreads();
  }

#pragma unroll
  for (int mi = 0; mi < 4; ++mi)
#pragma unroll
    for (int ni = 0; ni < 4; ++ni) {
      int n = n0 + wc * 64 + ni * 16 + fr;
      if (n >= N) continue;
      float bv = biasb ? biasb[n] : 0.f;
#pragma unroll
      for (int r = 0; r < 4; ++r) {
        int m = m0 + wr * 64 + mi * 16 + kh * 4 + r;
        if (m >= M) continue;
        float v = acc[mi][ni][r] + bv;
        if (act == 1) v = (v > 20.f) ? v : log1pf(__expf(v));
        Cb[(long)m * ldc + n] = v;
      }
    }
}

// -------- causal conv (sums SKI in_proj partials) + silu -> fp32 + bf16 hi/lo --------
__global__ void conv_silu_kernel(const float* __restrict__ xz_p,
                                 const float* __restrict__ cw,
                                 const float* __restrict__ cb,
                                 float* __restrict__ xc,
                                 u16* __restrict__ xch, u16* __restrict__ xcl) {
  const long PZ = (long)L_SEQ * 2 * DI;
  int dir = blockIdx.y;
  int idx = blockIdx.x * 256 + threadIdx.x;
  int d = idx % DI;
  int t = idx / DI;
  const float* w = cw + ((long)dir * DI + d) * 4;
  float acc = cb[dir * DI + d];
#pragma unroll
  for (int k = 0; k < 4; ++k) {
    int tau = t + k - 3;
    if (tau >= 0) {
      int tsrc = dir ? (L_SEQ - 1 - tau) : tau;
      long o = (long)tsrc * (2 * DI) + d;
      float xv = xz_p[o] + xz_p[o + PZ] + xz_p[o + 2 * PZ];
      acc += w[k] * xv;
    }
  }
  float s = acc / (1.f + __expf(-acc));
  long o = ((long)dir * L_SEQ + t) * DI + d;
  xc[o] = s;
  u16 h, l;
  split2(s, h, l);
  xch[o] = h;
  xcl[o] = l;
}

// -------- x_proj split-K reduce: dbl fp32 + d48 bf16 hi/lo --------
__global__ void xreduce_kernel(const float* __restrict__ dbl_p,
                               float* __restrict__ dbl,
                               u16* __restrict__ d48h, u16* __restrict__ d48l) {
  int idx = blockIdx.x * 256 + threadIdx.x;
  if (idx >= 2 * L_SEQ * 80) return;
  int j = idx % 80;
  int td = idx / 80;
  int dir = td / L_SEQ;
  int t = td - dir * L_SEQ;
  const float* p = dbl_p + (long)dir * SKX * L_SEQ * 80 + (long)t * 80 + j;
  float v = 0.f;
#pragma unroll
  for (int q = 0; q < SKX; ++q) v += p[(long)q * L_SEQ * 80];
  dbl[((long)dir * L_SEQ + t) * 80 + j] = v;
  if (j < DTRANK) {
    u16 h, l;
    split2(v, h, l);
    long o = ((long)dir * L_SEQ + t) * DTRANK + j;
    d48h[o] = h;
    d48l[o] = l;
  }
}

// ---------------- fused chunked selective scan (pass1 + fixup + pass2) ----------------
// grid (DI/8, 2); block 256 = 8 d-channels x 32 chunks
__global__ __launch_bounds__(256) void scan_all(
    const float* __restrict__ dtv_arr,  // (2,L,DI) softplus'ed dt
    const float* __restrict__ xc,       // (2,L,DI)
    const float* __restrict__ dbl,      // (2,L,80)
    const float* __restrict__ xz_p,     // SKI partials, z at [., DI+d]
    const float* __restrict__ A_log,    // (2,DI,16)
    const float* __restrict__ Dsk,      // (2,DI)
    float* __restrict__ y) {            // (2,L,DI) un-reversed
  const long PZ = (long)L_SEQ * 2 * DI;
  int dir = blockIdx.y;
  int d0 = blockIdx.x * 8;
  int tid = threadIdx.x;
  __shared__ float Q[8][NC][DSTATE];  // 16 KB
  __shared__ float Sv[8][NC];

  const float* dtp = dtv_arr + (long)dir * L_SEQ * DI;
  const float* xcp = xc + (long)dir * L_SEQ * DI;
  const float* dblp = dbl + (long)dir * L_SEQ * 80;

  int dl = tid & 7, c = tid >> 3;
  int d = d0 + dl;
  float negA[DSTATE];
#pragma unroll
  for (int n = 0; n < DSTATE; ++n)
    negA[n] = -__expf(A_log[((long)dir * DI + d) * DSTATE + n]);

  int t0 = c * CLEN, t1 = min(t0 + CLEN, L_SEQ);
  // pass 1: chunk-local scan
  {
    float h[DSTATE];
#pragma unroll
    for (int n = 0; n < DSTATE; ++n) h[n] = 0.f;
    float S = 0.f;
    for (int t = t0; t < t1; ++t) {
      float dt = dtp[(long)t * DI + d];
      float u = xcp[(long)t * DI + d];
      float du = dt * u;
      S += dt;
      const float4* B4 = (const float4*)(dblp + (long)t * 80 + DTRANK);
      float4 b0 = B4[0], b1 = B4[1], b2 = B4[2], b3 = B4[3];
      float Bv[DSTATE] = {b0.x, b0.y, b0.z, b0.w, b1.x, b1.y, b1.z, b1.w,
                          b2.x, b2.y, b2.z, b2.w, b3.x, b3.y, b3.z, b3.w};
#pragma unroll
      for (int n = 0; n < DSTATE; ++n)
        h[n] = h[n] * __expf(dt * negA[n]) + du * Bv[n];
    }
    Sv[dl][c] = S;
#pragma unroll
    for (int n = 0; n < DSTATE; ++n) Q[dl][c][n] = h[n];
  }
  __syncthreads();
  // fix-up: 128 threads (dl, n); Q becomes chunk-start states
  if (tid < 128) {
    int fdl = tid >> 4, n = tid & 15;
    int fd = d0 + fdl;
    float nA = -__expf(A_log[((long)dir * DI + fd) * DSTATE + n]);
    float h = 0.f;
    for (int cc = 0; cc < NC; ++cc) {
      float S = Sv[fdl][cc];
      float q = Q[fdl][cc][n];
      Q[fdl][cc][n] = h;
      h = h * __expf(nA * S) + q;
    }
  }
  __syncthreads();
  // pass 2: re-scan from chunk-start, emit gated y
  {
    float h[DSTATE];
#pragma unroll
    for (int n = 0; n < DSTATE; ++n) h[n] = Q[dl][c][n];
    float dskip = Dsk[dir * DI + d];
    for (int t = t0; t < t1; ++t) {
      float dt = dtp[(long)t * DI + d];
      float u = xcp[(long)t * DI + d];
      float du = dt * u;
      const float4* B4 = (const float4*)(dblp + (long)t * 80 + DTRANK);
      float4 b0 = B4[0], b1 = B4[1], b2 = B4[2], b3 = B4[3];
      float4 c0 = B4[4], c1 = B4[5], c2 = B4[6], c3 = B4[7];
      float Bv[DSTATE] = {b0.x, b0.y, b0.z, b0.w, b1.x, b1.y, b1.z, b1.w,
                          b2.x, b2.y, b2.z, b2.w, b3.x, b3.y, b3.z, b3.w};
      float Cv[DSTATE] = {c0.x, c0.y, c0.z, c0.w, c1.x, c1.y, c1.z, c1.w,
                          c2.x, c2.y, c2.z, c2.w, c3.x, c3.y, c3.z, c3.w};
      float acc = 0.f;
#pragma unroll
      for (int n = 0; n < DSTATE; ++n) {
        h[n] = h[n] * __expf(dt * negA[n]) + du * Bv[n];
        acc += h[n] * Cv[n];
      }
      int tsrc = dir ? (L_SEQ - 1 - t) : t;
      long zo = (long)tsrc * (2 * DI) + DI + d;
      float zv = xz_p[zo] + xz_p[zo + PZ] + xz_p[zo + 2 * PZ];
      float sz = zv / (1.f + __expf(-zv));
      y[((long)dir * L_SEQ + tsrc) * DI + d] = (acc + dskip * u) * sz;
    }
  }
}

// ---------------- (yf+yb)*0.5 -> bf16 hi/lo ----------------
__global__ void yavg_kernel(const float* __restrict__ yf,
                            const float* __restrict__ yb,
                            u16* __restrict__ yh, u16* __restrict__ yl) {
  long i = (long)blockIdx.x * 256 + threadIdx.x;
  if (i >= (long)L_SEQ * DI / 4) return;
  float4 a = ((const float4*)yf)[i];
  float4 b = ((const float4*)yb)[i];
  ushort4 h, l;
  split2(0.5f * (a.x + b.x), h.x, l.x);
  split2(0.5f * (a.y + b.y), h.y, l.y);
  split2(0.5f * (a.z + b.z), h.z, l.z);
  split2(0.5f * (a.w + b.w), h.w, l.w);
  ((ushort4*)yh)[i] = h;
  ((ushort4*)yl)[i] = l;
}

// ---------------- final rmsnorm(token 256) + head (sums 8 partials) ----------------
__global__ void head_kernel(const float* __restrict__ residual,
                            const float* __restrict__ hp, long pstr,
                            const float* __restrict__ nfw,
                            const float* __restrict__ hw,
                            const float* __restrict__ hb,
                            float* __restrict__ out) {
  int j = blockIdx.x;
  int tid = threadIdx.x;  // 256
  const float* r = residual + (long)256 * DM;
  float ss = 0.f, dp = 0.f;
#pragma unroll
  for (int i = 0; i < 3; ++i) {
    int c = tid + i * 256;
    float v = r[c];
    for (int p = 0; p < SKO; ++p) v += hp[(long)p * pstr + (long)256 * DM + c];
    ss += v * v;
    dp += v * nfw[c] * hw[(long)j * DM + c];
  }
#pragma unroll
  for (int o = 32; o; o >>= 1) {
    ss += __shfl_down(ss, o, 64);
    dp += __shfl_down(dp, o, 64);
  }
  __shared__ float s1[4], s2[4];
  if ((tid & 63) == 0) {
    s1[tid >> 6] = ss;
    s2[tid >> 6] = dp;
  }
  __syncthreads();
  if (tid == 0) {
    float tot = s1[0] + s1[1] + s1[2] + s1[3];
    float d = s2[0] + s2[1] + s2[2] + s2[3];
    out[j] = d * rsqrtf(tot / (float)DM + 1e-5f) + hb[j];
  }
}

extern "C" void kernel_launch(void* const* d_in, const int* in_sizes, int n_in,
                              void* d_out, int out_size, void* d_ws, size_t ws_size,
                              hipStream_t stream) {
  const float* x        = (const float*)d_in[0];
  const float* patch_w  = (const float*)d_in[1];
  const float* patch_b  = (const float*)d_in[2];
  const float* cls_tok  = (const float*)d_in[3];
  const float* pos_emb  = (const float*)d_in[4];
  const float* in_proj  = (const float*)d_in[5];
  const float* conv_w   = (const float*)d_in[6];
  const float* conv_b   = (const float*)d_in[7];
  const float* xproj_w  = (const float*)d_in[8];
  const float* dtproj_w = (const float*)d_in[9];
  const float* dtproj_b = (const float*)d_in[10];
  const float* A_log    = (const float*)d_in[11];
  const float* D_skip   = (const float*)d_in[12];
  const float* out_proj = (const float*)d_in[13];
  const float* norm_w   = (const float*)d_in[14];
  const float* norm_f_w = (const float*)d_in[15];
  const float* head_w   = (const float*)d_in[16];
  const float* head_b   = (const float*)d_in[17];
  float* out = (float*)d_out;

  const long PHN = (long)L_SEQ * DM;
  const long PZ  = (long)L_SEQ * 2 * DI;

  float* ws = (float*)d_ws;
  float* residual = ws; ws += PHN;
  float* xz_p     = ws; ws += SKI * PZ;
  float* xc       = ws; ws += (long)2 * L_SEQ * DI;
  float* dbl      = ws; ws += (long)2 * L_SEQ * 80;
  float* dbl_p    = ws; ws += (long)2 * SKX * L_SEQ * 80;
  float* dtb      = ws; ws += (long)2 * L_SEQ * DI;
  float* yb       = ws; ws += (long)2 * L_SEQ * DI;
  float* hid_p    = ws; ws += (long)SKO * PHN;

  u16* wsu = (u16*)ws;
  const long N_HN  = PHN;
  const long N_XC  = (long)2 * L_SEQ * DI;
  const long N_D48 = (long)2 * L_SEQ * DTRANK;
  const long N_YA  = (long)L_SEQ * DI;
  const long N_WI  = (long)DEPTH * 2 * DI * DM;
  const long N_WX  = (long)DEPTH * 2 * 80 * DI;
  const long N_WD  = (long)DEPTH * 2 * DI * DTRANK;
  const long N_WO  = (long)DEPTH * DM * DI;
  u16* hn_h  = wsu; wsu += N_HN;
  u16* hn_l  = wsu; wsu += N_HN;
  u16* xc_h  = wsu; wsu += N_XC;
  u16* xc_l  = wsu; wsu += N_XC;
  u16* d48_h = wsu; wsu += N_D48;
  u16* d48_l = wsu; wsu += N_D48;
  u16* ya_h  = wsu; wsu += N_YA;
  u16* ya_l  = wsu; wsu += N_YA;
  u16* wi_h  = wsu; wsu += N_WI;
  u16* wi_l  = wsu; wsu += N_WI;
  u16* wx_h  = wsu; wsu += N_WX;
  u16* wx_l  = wsu; wsu += N_WX;
  u16* wd_h  = wsu; wsu += N_WD;
  u16* wd_l  = wsu; wsu += N_WD;
  u16* wo_h  = wsu; wsu += N_WO;
  u16* wo_l  = wsu; wsu += N_WO;

  wconvert_kernel<<<2048, 256, 0, stream>>>(in_proj,  wi_h, wi_l, N_WI / 4);
  wconvert_kernel<<<512,  256, 0, stream>>>(xproj_w,  wx_h, wx_l, N_WX / 4);
  wconvert_kernel<<<512,  256, 0, stream>>>(dtproj_w, wd_h, wd_l, N_WD / 4);
  wconvert_kernel<<<2048, 256, 0, stream>>>(out_proj, wo_h, wo_l, N_WO / 4);

  // layer-0 hidden goes into hid_p part 0
  patch_embed_kernel<<<dim3(3, L_SEQ), 256, 0, stream>>>(
      x, patch_w, patch_b, cls_tok, pos_emb, hid_p, residual);

  for (int l = 0; l < DEPTH; ++l) {
    const u16* wih = wi_h + (long)l * 2 * DI * DM;
    const u16* wil = wi_l + (long)l * 2 * DI * DM;
    const u16* wxh = wx_h + (long)l * 2 * 80 * DI;
    const u16* wxl = wx_l + (long)l * 2 * 80 * DI;
    const u16* wdh = wd_h + (long)l * 2 * DI * DTRANK;
    const u16* wdl = wd_l + (long)l * 2 * DI * DTRANK;
    const u16* woh = wo_h + (long)l * DM * DI;
    const u16* wol = wo_l + (long)l * DM * DI;
    const float* cw  = conv_w   + (long)l * 2 * DI * 4;
    const float* cb  = conv_b   + (long)l * 2 * DI;
    const float* db  = dtproj_b + (long)l * 2 * DI;
    const float* Al  = A_log    + (long)l * 2 * DI * DSTATE;
    const float* Dk  = D_skip   + (long)l * 2 * DI;
    const float* nw  = norm_w   + (long)l * DM;

    rmsnorm_kernel<<<L_SEQ, 256, 0, stream>>>(
        hid_p, (l == 0) ? 1 : SKO, PHN, residual, hn_h, hn_l, nw);

    // xz partials(3): (513,3072) = hn @ ipw^T, split-K=3
    gemm128<<<dim3(24, 5, SKI), 256, 0, stream>>>(
        hn_h, hn_l, wih, wil, xz_p, L_SEQ, 2 * DI, DM, DM, DM, 2 * DI,
        0, 0, 0, SKI, DM / SKI, PZ, nullptr, 0, 0);

    conv_silu_kernel<<<dim3(3078, 2), 256, 0, stream>>>(xz_p, cw, cb, xc, xc_h, xc_l);

    // dbl partials(8 per dir): (513,80) = xc @ xw^T, batched over dir
    gemm128<<<dim3(1, 5, 2 * SKX), 256, 0, stream>>>(
        xc_h, xc_l, wxh, wxl, dbl_p, L_SEQ, 80, DI, DI, DI, 80,
        (long)L_SEQ * DI, (long)80 * DI, (long)SKX * L_SEQ * 80,
        SKX, DI / SKX, (long)L_SEQ * 80, nullptr, 0, 0);

    xreduce_kernel<<<(2 * L_SEQ * 80 + 255) / 256, 256, 0, stream>>>(
        dbl_p, dbl, d48_h, d48_l);

    // dtb = softplus(d48 @ dw^T + db), batched over dir, no split-K
    gemm128<<<dim3(12, 5, 2), 256, 0, stream>>>(
        d48_h, d48_l, wdh, wdl, dtb, L_SEQ, DI, DTRANK, DTRANK, DTRANK, DI,
        (long)L_SEQ * DTRANK, (long)DI * DTRANK, (long)L_SEQ * DI,
        1, DTRANK, 0, db, DI, 1);

    // fused chunked scan
    scan_all<<<dim3(DI / 8, 2), 256, 0, stream>>>(
        dtb, xc, dbl, xz_p, Al, Dk, yb);

    yavg_kernel<<<(L_SEQ * DI / 4 + 255) / 256, 256, 0, stream>>>(
        yb, yb + (long)L_SEQ * DI, ya_h, ya_l);

    // hidden partials(8): (513,768) = yavg @ opw^T, split-K=8
    gemm128<<<dim3(6, 5, SKO), 256, 0, stream>>>(
        ya_h, ya_l, woh, wol, hid_p, L_SEQ, DM, DI, DI, DI, DM,
        0, 0, 0, SKO, DI / SKO, PHN, nullptr, 0, 0);
  }

  head_kernel<<<NCLS, 256, 0, stream>>>(residual, hid_p, PHN,
                                        norm_f_w, head_w, head_b, out);
}